// Round 2
// baseline (607.135 us; speedup 1.0000x reference)
//
#include <hip/hip_runtime.h>

// 100 / ln(2): reference divides by T=0.01 then e-base LSE; we work in base-2
// (v_exp_f32 is natively 2^x).
#define SCALE 144.269504088896340736f
#define TOL   1e-3f

typedef float v2 __attribute__((ext_vector_type(2)));

// DPP move helper (compile-time ctrl). bound_ctrl=true, all rows/banks.
template <int CTRL>
__device__ __forceinline__ float dppf(float x) {
    return __builtin_bit_cast(
        float, __builtin_amdgcn_update_dpp(0, __builtin_bit_cast(int, x),
                                           CTRL, 0xF, 0xF, true));
}
// Reduce over the 4 "b" lanes (quad): quad_perm ror1 (0x39), ror2 (0x4E).
__device__ __forceinline__ float qsum(float x) {
    x += dppf<0x39>(x); x += dppf<0x4E>(x); return x;
}
__device__ __forceinline__ float qmax(float x) {
    x = fmaxf(x, dppf<0x39>(x)); x = fmaxf(x, dppf<0x4E>(x)); return x;
}
// Reduce over the 4 "a" lanes: row_ror:4 (0x124), row_ror:8 (0x128).
__device__ __forceinline__ float asum(float x) {
    x += dppf<0x124>(x); x += dppf<0x128>(x); return x;
}
__device__ __forceinline__ float amax(float x) {
    x = fmaxf(x, dppf<0x124>(x)); x = fmaxf(x, dppf<0x128>(x)); return x;
}

// One matrix per 16-lane DPP row; 4 per wave; 16 per 256-thread block.
// Lane (q,a,b) holds C[a*9+r][b*9+j], r,j in [0,9). Columns stored as
// 4 float2 pairs (j=0..7) + 1 scalar tail (j=8) to feed v_pk_fma_f32.
__global__ __launch_bounds__(256, 4) void sinkhorn_kernel(
    const float* __restrict__ in, float* __restrict__ out) {
    const int lane = threadIdx.x & 63;
    const int wv   = threadIdx.x >> 6;
    const int a    = (lane >> 2) & 3;
    const int b    = lane & 3;
    const int m    = blockIdx.x * 16 + wv * 4 + (lane >> 4);

    const float* src = in  + (size_t)m * 1296 + (a * 9) * 36 + b * 9;
    float*       dst = out + (size_t)m * 1296 + (a * 9) * 36 + b * 9;

    v2 Cp[9][4]; float Cl[9];
    #pragma unroll
    for (int r = 0; r < 9; ++r) {
        #pragma unroll
        for (int p = 0; p < 4; ++p) {
            Cp[r][p].x = src[r * 36 + 2 * p];
            Cp[r][p].y = src[r * 36 + 2 * p + 1];
        }
        Cl[r] = src[r * 36 + 8];
    }

    // a2[r] = row max of raw L (max is scale-invariant; scale later).
    float a2[9];
    #pragma unroll
    for (int r = 0; r < 9; ++r) {
        float mx = fmaxf(Cp[r][0].x, Cp[r][0].y);
        #pragma unroll
        for (int p = 1; p < 4; ++p) mx = fmaxf(mx, fmaxf(Cp[r][p].x, Cp[r][p].y));
        a2[r] = qmax(fmaxf(mx, Cl[r]));
    }

    // C <- L - a2[r]; track per-packed-col max for b2.
    v2 cm[4]; float cml = -3.4e38f;
    #pragma unroll
    for (int p = 0; p < 4; ++p) { cm[p].x = -3.4e38f; cm[p].y = -3.4e38f; }
    #pragma unroll
    for (int r = 0; r < 9; ++r) {
        v2 na = {-a2[r], -a2[r]};
        #pragma unroll
        for (int p = 0; p < 4; ++p) {
            Cp[r][p] += na;
            cm[p].x = fmaxf(cm[p].x, Cp[r][p].x);
            cm[p].y = fmaxf(cm[p].y, Cp[r][p].y);
        }
        Cl[r] -= a2[r];
        cml = fmaxf(cml, Cl[r]);
    }

    // b2[j] = colmax(L - a2) <= 0; p[j] = 2^(b2*SCALE) in (0,1].
    v2 nb2s[4], p2[4];
    #pragma unroll
    for (int p = 0; p < 4; ++p) {
        float bx = amax(cm[p].x), by = amax(cm[p].y);
        nb2s[p].x = -bx * SCALE; nb2s[p].y = -by * SCALE;
        p2[p].x = __builtin_amdgcn_exp2f(bx * SCALE);
        p2[p].y = __builtin_amdgcn_exp2f(by * SCALE);
    }
    float bl  = amax(cml);
    float nbl = -bl * SCALE;
    float pl  = __builtin_amdgcn_exp2f(bl * SCALE);

    // C = 2^((L - a2 - b2)*SCALE) in (0,1]; every row AND col contains a 1.
    const v2 S2 = {SCALE, SCALE};
    #pragma unroll
    for (int r = 0; r < 9; ++r) {
        #pragma unroll
        for (int p = 0; p < 4; ++p) {
            v2 t = Cp[r][p] * S2 + nb2s[p];  // pk_fma
            Cp[r][p].x = __builtin_amdgcn_exp2f(t.x);
            Cp[r][p].y = __builtin_amdgcn_exp2f(t.y);
        }
        Cl[r] = __builtin_amdgcn_exp2f(Cl[r] * SCALE + nbl);
    }

    // u^(1)_r = 1 / sum_j 2^(L-a2) = 1 / sum_j C_rj * p_j  (no exp pass).
    float u[9];
    #pragma unroll
    for (int r = 0; r < 9; ++r) {
        v2 acc = Cp[r][0] * p2[0];
        #pragma unroll
        for (int p = 1; p < 4; ++p) acc = Cp[r][p] * p2[p] + acc;  // pk_fma
        float t = fmaf(Cl[r], pl, acc.x + acc.y);
        u[r] = __builtin_amdgcn_rcpf(qsum(t));
    }

    // w^(1)_j = 1 / sum_r C_rj u_r  (first col step).
    v2 w2[4]; float wl;
    {
        v2 acc2[4]; float accl = 0.f;
        #pragma unroll
        for (int p = 0; p < 4; ++p) { acc2[p].x = 0.f; acc2[p].y = 0.f; }
        #pragma unroll
        for (int r = 0; r < 9; ++r) {
            v2 ur = {u[r], u[r]};
            #pragma unroll
            for (int p = 0; p < 4; ++p) acc2[p] = Cp[r][p] * ur + acc2[p];
            accl = fmaf(Cl[r], u[r], accl);
        }
        #pragma unroll
        for (int p = 0; p < 4; ++p) {
            w2[p].x = __builtin_amdgcn_rcpf(asum(acc2[p].x));
            w2[p].y = __builtin_amdgcn_rcpf(asum(acc2[p].y));
        }
        wl = __builtin_amdgcn_rcpf(asum(accl));
    }

    // Up to 20 more iterations; early-exit when w stabilizes (all 4 matrices
    // in the wave). Worst case = exactly 21 total iterations, same as ref.
    #pragma unroll 1
    for (int it = 0; it < 20; ++it) {
        // row step: u = 1/(C w)
        #pragma unroll
        for (int r = 0; r < 9; ++r) {
            v2 acc = Cp[r][0] * w2[0];
            #pragma unroll
            for (int p = 1; p < 4; ++p) acc = Cp[r][p] * w2[p] + acc;
            float t = fmaf(Cl[r], wl, acc.x + acc.y);
            u[r] = __builtin_amdgcn_rcpf(qsum(t));
        }
        // col step: w = 1/(C^T u), track max relative change of w.
        v2 acc2[4]; float accl = 0.f;
        #pragma unroll
        for (int p = 0; p < 4; ++p) { acc2[p].x = 0.f; acc2[p].y = 0.f; }
        #pragma unroll
        for (int r = 0; r < 9; ++r) {
            v2 ur = {u[r], u[r]};
            #pragma unroll
            for (int p = 0; p < 4; ++p) acc2[p] = Cp[r][p] * ur + acc2[p];
            accl = fmaf(Cl[r], u[r], accl);
        }
        float mx = 0.f;
        #pragma unroll
        for (int p = 0; p < 4; ++p) {
            float dx = asum(acc2[p].x), dy = asum(acc2[p].y);
            mx = fmaxf(mx, fabsf(fmaf(dx, w2[p].x, -1.f)));
            mx = fmaxf(mx, fabsf(fmaf(dy, w2[p].y, -1.f)));
            w2[p].x = __builtin_amdgcn_rcpf(dx);
            w2[p].y = __builtin_amdgcn_rcpf(dy);
        }
        float dl = asum(accl);
        mx = fmaxf(mx, fabsf(fmaf(dl, wl, -1.f)));
        wl = __builtin_amdgcn_rcpf(dl);
        mx = qmax(mx);                 // uniform across the 16-lane group
        if (__all(mx < TOL)) break;    // all 4 matrices converged
    }

    // P = C * u_r * w_j
    #pragma unroll
    for (int r = 0; r < 9; ++r) {
        v2 ur = {u[r], u[r]};
        #pragma unroll
        for (int p = 0; p < 4; ++p) {
            v2 t = Cp[r][p] * ur * w2[p];  // pk_mul x2
            dst[r * 36 + 2 * p]     = t.x;
            dst[r * 36 + 2 * p + 1] = t.y;
        }
        dst[r * 36 + 8] = Cl[r] * u[r] * wl;
    }
}

extern "C" void kernel_launch(void* const* d_in, const int* in_sizes, int n_in,
                              void* d_out, int out_size, void* d_ws, size_t ws_size,
                              hipStream_t stream) {
    const float* in  = (const float*)d_in[0];
    float*       out = (float*)d_out;
    sinkhorn_kernel<<<dim3(4096), dim3(256), 0, stream>>>(in, out);
}

// Round 3
// 593.281 us; speedup vs baseline: 1.0234x; 1.0234x over previous
//
#include <hip/hip_runtime.h>

// 100 / ln(2): reference divides by T=0.01 then e-base LSE; we work base-2
// (v_exp_f32 is natively 2^x).
#define SCALE 144.269504088896340736f
#define TOL   1e-3f
#define NINF  -3.4e38f

typedef float v2 __attribute__((ext_vector_type(2)));
typedef float v4 __attribute__((ext_vector_type(4)));

template <int CTRL>
__device__ __forceinline__ float dppf(float x) {
    return __builtin_bit_cast(
        float, __builtin_amdgcn_update_dpp(0, __builtin_bit_cast(int, x),
                                           CTRL, 0xF, 0xF, true));
}
// Reduce over the 4 "b" lanes (quad_perm ror1 0x39, ror2 0x4E).
__device__ __forceinline__ float qsum(float x) {
    x += dppf<0x39>(x); x += dppf<0x4E>(x); return x;
}
__device__ __forceinline__ float qmax(float x) {
    x = fmaxf(x, dppf<0x39>(x)); x = fmaxf(x, dppf<0x4E>(x)); return x;
}
// Reduce over the 4 "a" lanes (row_ror:4 0x124, row_ror:8 0x128).
__device__ __forceinline__ float asum(float x) {
    x += dppf<0x124>(x); x += dppf<0x128>(x); return x;
}
__device__ __forceinline__ float amax(float x) {
    x = fmaxf(x, dppf<0x124>(x)); x = fmaxf(x, dppf<0x128>(x)); return x;
}
__device__ __forceinline__ v2 vmax2(v2 p, v2 q) {
    return (v2){fmaxf(p.x, q.x), fmaxf(p.y, q.y)};
}

// One matrix per 16-lane DPP row; 4 per wave; 16 per 256-thread block.
// Lane (q,a,b): rows a*9..a*9+8; cols {4b..4b+3, 16+4b..16+4b+3, 32+b}.
// This column interleave makes every load/store a coalesced dwordx4/dword
// (4-lane groups cover contiguous 64B) while keeping the same DPP-reduce
// structure: row sums = local + qsum over b; col sums = local + asum over a.
__global__ __launch_bounds__(256, 4) void sinkhorn_kernel(
    const float* __restrict__ in, float* __restrict__ out) {
    const int lane = threadIdx.x & 63;
    const int wv   = threadIdx.x >> 6;
    const int a    = (lane >> 2) & 3;
    const int b    = lane & 3;
    const int m    = blockIdx.x * 16 + wv * 4 + (lane >> 4);

    const size_t base = (size_t)m * 1296 + (size_t)(a * 9) * 36;
    const float* src  = in  + base;
    float*       dst  = out + base;
    const int o0 = 4 * b;
    const int o1 = 16 + 4 * b;
    const int ot = 32 + b;

    // A[r][0..1] = cols 4b..4b+3; A[r][2..3] = cols 16+4b..; T[r] = col 32+b.
    v2 A[9][4]; float T[9];
    #pragma unroll
    for (int r = 0; r < 9; ++r) {
        v4 c0 = *(const v4*)(src + r * 36 + o0);
        v4 c1 = *(const v4*)(src + r * 36 + o1);
        A[r][0] = (v2){c0.x, c0.y}; A[r][1] = (v2){c0.z, c0.w};
        A[r][2] = (v2){c1.x, c1.y}; A[r][3] = (v2){c1.z, c1.w};
        T[r]    = src[r * 36 + ot];
    }

    // a2[r] = row max of raw L.
    float a2[9];
    #pragma unroll
    for (int r = 0; r < 9; ++r) {
        v2 m2 = vmax2(vmax2(A[r][0], A[r][1]), vmax2(A[r][2], A[r][3]));
        a2[r] = qmax(fmaxf(fmaxf(m2.x, m2.y), T[r]));
    }

    // L <- L - a2[r]; track per-col maxes.
    v2 cm[4]; float cmt = NINF;
    #pragma unroll
    for (int p = 0; p < 4; ++p) { cm[p].x = NINF; cm[p].y = NINF; }
    #pragma unroll
    for (int r = 0; r < 9; ++r) {
        v2 na = {-a2[r], -a2[r]};
        #pragma unroll
        for (int p = 0; p < 4; ++p) {
            A[r][p] += na;
            cm[p] = vmax2(cm[p], A[r][p]);
        }
        T[r] -= a2[r];
        cmt = fmaxf(cmt, T[r]);
    }

    // b2[j] = colmax(L - a2) <= 0; p2 = 2^(b2*SCALE) in (0,1].
    v2 nb2[4], p2[4];
    #pragma unroll
    for (int p = 0; p < 4; ++p) {
        float bx = amax(cm[p].x), by = amax(cm[p].y);
        nb2[p].x = -bx * SCALE; nb2[p].y = -by * SCALE;
        p2[p].x = __builtin_amdgcn_exp2f(bx * SCALE);
        p2[p].y = __builtin_amdgcn_exp2f(by * SCALE);
    }
    float bt  = amax(cmt);
    float nbt = -bt * SCALE;
    float pt  = __builtin_amdgcn_exp2f(bt * SCALE);

    // C = 2^((L-a2-b2)*SCALE) in (0,1]; every row AND col contains a 1.
    const v2 S2 = {SCALE, SCALE};
    #pragma unroll
    for (int r = 0; r < 9; ++r) {
        #pragma unroll
        for (int p = 0; p < 4; ++p) {
            v2 t = A[r][p] * S2 + nb2[p];  // pk_fma
            A[r][p].x = __builtin_amdgcn_exp2f(t.x);
            A[r][p].y = __builtin_amdgcn_exp2f(t.y);
        }
        T[r] = __builtin_amdgcn_exp2f(T[r] * SCALE + nbt);
    }

    // u^(1)_r = 1 / sum_j C_rj p_j  (first row step, no extra exp pass).
    float u[9];
    #pragma unroll
    for (int r = 0; r < 9; ++r) {
        v2 acc = A[r][0] * p2[0];
        #pragma unroll
        for (int p = 1; p < 4; ++p) acc = A[r][p] * p2[p] + acc;
        float t = fmaf(T[r], pt, acc.x + acc.y);
        u[r] = __builtin_amdgcn_rcpf(qsum(t));
    }

    // w^(1)_j = 1 / sum_r C_rj u_r.
    v2 wA[4]; float wt;
    {
        v2 acc2[4]; float acct = 0.f;
        #pragma unroll
        for (int p = 0; p < 4; ++p) { acc2[p].x = 0.f; acc2[p].y = 0.f; }
        #pragma unroll
        for (int r = 0; r < 9; ++r) {
            v2 ur = {u[r], u[r]};
            #pragma unroll
            for (int p = 0; p < 4; ++p) acc2[p] = A[r][p] * ur + acc2[p];
            acct = fmaf(T[r], u[r], acct);
        }
        #pragma unroll
        for (int p = 0; p < 4; ++p) {
            wA[p].x = __builtin_amdgcn_rcpf(asum(acc2[p].x));
            wA[p].y = __builtin_amdgcn_rcpf(asum(acc2[p].y));
        }
        wt = __builtin_amdgcn_rcpf(asum(acct));
    }

    // Up to 20 more iterations; early-exit when w stabilizes for all 4
    // matrices in the wave. Worst case = 21 iterations total (same as ref).
    #pragma unroll 1
    for (int it = 0; it < 20; ++it) {
        #pragma unroll
        for (int r = 0; r < 9; ++r) {
            v2 acc = A[r][0] * wA[0];
            #pragma unroll
            for (int p = 1; p < 4; ++p) acc = A[r][p] * wA[p] + acc;
            float t = fmaf(T[r], wt, acc.x + acc.y);
            u[r] = __builtin_amdgcn_rcpf(qsum(t));
        }
        v2 acc2[4]; float acct = 0.f;
        #pragma unroll
        for (int p = 0; p < 4; ++p) { acc2[p].x = 0.f; acc2[p].y = 0.f; }
        #pragma unroll
        for (int r = 0; r < 9; ++r) {
            v2 ur = {u[r], u[r]};
            #pragma unroll
            for (int p = 0; p < 4; ++p) acc2[p] = A[r][p] * ur + acc2[p];
            acct = fmaf(T[r], u[r], acct);
        }
        float mx = 0.f;
        #pragma unroll
        for (int p = 0; p < 4; ++p) {
            float dx = asum(acc2[p].x), dy = asum(acc2[p].y);
            mx = fmaxf(mx, fabsf(fmaf(dx, wA[p].x, -1.f)));
            mx = fmaxf(mx, fabsf(fmaf(dy, wA[p].y, -1.f)));
            wA[p].x = __builtin_amdgcn_rcpf(dx);
            wA[p].y = __builtin_amdgcn_rcpf(dy);
        }
        float dt = asum(acct);
        mx = fmaxf(mx, fabsf(fmaf(dt, wt, -1.f)));
        wt = __builtin_amdgcn_rcpf(dt);
        mx = qmax(mx);
        if (__all(mx < TOL)) break;
    }

    // P = C * u_r * w_j  (coalesced dwordx4 stores -> full 64B lines).
    #pragma unroll
    for (int r = 0; r < 9; ++r) {
        v2 ur = {u[r], u[r]};
        v2 t0 = A[r][0] * ur * wA[0];
        v2 t1 = A[r][1] * ur * wA[1];
        v2 t2 = A[r][2] * ur * wA[2];
        v2 t3 = A[r][3] * ur * wA[3];
        *(v4*)(dst + r * 36 + o0) = (v4){t0.x, t0.y, t1.x, t1.y};
        *(v4*)(dst + r * 36 + o1) = (v4){t2.x, t2.y, t3.x, t3.y};
        dst[r * 36 + ot] = T[r] * u[r] * wt;
    }
}

extern "C" void kernel_launch(void* const* d_in, const int* in_sizes, int n_in,
                              void* d_out, int out_size, void* d_ws, size_t ws_size,
                              hipStream_t stream) {
    const float* in  = (const float*)d_in[0];
    float*       out = (float*)d_out;
    sinkhorn_kernel<<<dim3(4096), dim3(256), 0, stream>>>(in, out);
}